// Round 3
// baseline (754.428 us; speedup 1.0000x reference)
//
#include <hip/hip_runtime.h>
#include <math.h>

// E2M1 (MXFP4) block weight quantizer, block=32, layer_max=6.0.
// Outputs concatenated in d_out (float32):
//   [0, N)        deq_weight          N = 8192*8192
//   [N, 2N)       encoded (0..15 as float)
//   [2N, 2N+B)    e8m0_scale + 127    B = N/32
//   [2N+B, 2N+2B) eps_base = 0.5*tanh(eps_param)
//
// R5: MEASUREMENT ROUND. R3 (broken coalescing) == R4 (perfect coalescing)
// within 1us killed the "kernel is pattern-bound at ~350us" certainty; the
// kernel has never appeared in rocprof top-5 (cutoff ~346us) so its counters
// have never been seen. This round: EXACT R2 body (the 688.4us anchor),
// executed 3x inside one dispatch (memory clobber between passes; output is
// a pure function of inputs so repetition is bit-identical).
//   -> dur_us = 688.4 + 2K gives the true kernel time K to ~1us.
//   -> the fused dispatch (~3K >= 500us) is forced into rocprof top-5,
//      exposing per-kernel hbm_gbps / VALUBusy / FETCH / WRITE / occupancy.
// Next round: K small -> revert to single launch, declare roofline.
//             K large -> counters say which pipe to attack.

constexpr long long OUT_F = 8192;
constexpr long long IN_F  = 8192;
constexpr long long NELEM = OUT_F * IN_F;      // 67108864
constexpr long long NBLK  = NELEM / 32;        // 2097152

__global__ __launch_bounds__(256) void e2m1_quant_kernel(
    const float* __restrict__ w,
    const float* __restrict__ eps_p,
    float* __restrict__ out)
{
    for (int pass = 0; pass < 3; ++pass) {
        // ---- body below is byte-identical to the R2 (688.4us) kernel ----
        const long long tid  = (long long)blockIdx.x * blockDim.x + threadIdx.x;
        const long long b    = tid >> 3;          // block index [0, NBLK)
        const int       sub  = (int)(tid & 7);    // lane-in-block
        const long long base = b * 32 + (long long)sub * 4;

        const float4 wv = *reinterpret_cast<const float4*>(w + base);

        float a = fmaxf(fmaxf(fabsf(wv.x), fabsf(wv.y)),
                        fmaxf(fabsf(wv.z), fabsf(wv.w)));
        a = fmaxf(a, __shfl_xor(a, 1));
        a = fmaxf(a, __shfl_xor(a, 2));
        a = fmaxf(a, __shfl_xor(a, 4));

        const float descale_div = a / 6.0f;
        float lf = __log2f(descale_div);
        lf = fmaxf(lf, -127.0f);
        const float e8 = ceilf(lf);
        const int   ei = (int)e8;
        const float rscale = ldexpf(1.0f, -ei);   // single v_ldexp_f32, exact pow2

        const float p  = eps_p[b];
        const float t  = fabsf(p);
        const float em = __expf(-2.0f * t);       // in (0,1]
        const float th = (1.0f - em) / (1.0f + em);
        const float ep = 0.5f * copysignf(th, p);

        const float vals[4] = {wv.x, wv.y, wv.z, wv.w};
        float deq[4], enc[4];

#pragma unroll
        for (int i = 0; i < 4; ++i) {
            const float wn = vals[i] * rscale;    // exact: mul by power of 2
            const float as = fmaxf(fabsf(wn) + ep, 0.0f);
            const int o = (as > 0.25f) + (as > 0.75f) + (as > 1.25f) + (as > 1.75f)
                        + (as > 2.5f)  + (as > 3.5f)  + (as > 5.0f);
            const int sbit = (wn <= 0.0f) ? 1 : 0;
            const float mant = (o < 2) ? (float)o * 0.5f
                                       : ldexpf(1.0f + (float)(o & 1) * 0.5f, (o >> 1) - 1);
            const float sgn = sbit ? -1.0f : 1.0f;
            deq[i] = ldexpf(mant * sgn, ei);      // exact: <=3 sig bits * pow2
            enc[i] = (float)(sbit * 8 + o);
        }

        *reinterpret_cast<float4*>(out + base) =
            make_float4(deq[0], deq[1], deq[2], deq[3]);
        *reinterpret_cast<float4*>(out + NELEM + base) =
            make_float4(enc[0], enc[1], enc[2], enc[3]);

        if (sub == 0) {
            out[2 * NELEM + b]        = e8 + 127.0f;  // e8m0_scale_uint8 as float
            out[2 * NELEM + NBLK + b] = ep;           // eps_base
        }
        // ---- end R2 body ----

        // Prevent cross-pass store elision / load caching: force the compiler
        // to treat each pass's memory ops as live and re-executed.
        asm volatile("" ::: "memory");
    }
}

extern "C" void kernel_launch(void* const* d_in, const int* in_sizes, int n_in,
                              void* d_out, int out_size, void* d_ws, size_t ws_size,
                              hipStream_t stream) {
    const float* w     = (const float*)d_in[0];   // weight_fp  [8192*8192]
    const float* eps_p = (const float*)d_in[1];   // eps_param  [2097152]
    float* out = (float*)d_out;

    const long long n_threads = NELEM / 4;        // 16,777,216
    const int block = 256;
    const int grid  = (int)(n_threads / block);   // 65,536
    e2m1_quant_kernel<<<grid, block, 0, stream>>>(w, eps_p, out);
}